// Round 6
// baseline (792.486 us; speedup 1.0000x reference)
//
#include <hip/hip_runtime.h>
#include <hip/hip_bf16.h>

#define DD 128   // hidden dim
#define SCB 256  // scan block size
#define CE  256  // edges per block in edge_pass

typedef __attribute__((ext_vector_type(8))) short bf16x8;
typedef __attribute__((ext_vector_type(4))) float f32x4;

__device__ __forceinline__ unsigned bf16_rne(float f) {
    unsigned u = __float_as_uint(f);
    return (u + 0x7fffu + ((u >> 16) & 1u)) >> 16;
}

// ---------------------------------------------------------------------------
// counting-sort preprocessing (sort edges by idx_i) -- unchanged
// ---------------------------------------------------------------------------
__global__ __launch_bounds__(256)
void hist_kernel(const int* __restrict__ idx_i, int* __restrict__ cnt, int E)
{
    const int e = blockIdx.x * 256 + threadIdx.x;
    if (e < E) atomicAdd(&cnt[idx_i[e]], 1);
}

__global__ __launch_bounds__(SCB)
void scan1_kernel(const int* __restrict__ cnt, int* __restrict__ exc,
                  int* __restrict__ bsum, int n)
{
    __shared__ int s[SCB];
    const int i = blockIdx.x * SCB + (int)threadIdx.x;
    const int v = (i < n) ? cnt[i] : 0;
    s[threadIdx.x] = v;
    __syncthreads();
    #pragma unroll
    for (int off = 1; off < SCB; off <<= 1) {
        int t = (threadIdx.x >= off) ? s[threadIdx.x - off] : 0;
        __syncthreads();
        s[threadIdx.x] += t;
        __syncthreads();
    }
    if (i < n) exc[i] = s[threadIdx.x] - v;
    if (threadIdx.x == SCB - 1) bsum[blockIdx.x] = s[threadIdx.x];
}

__global__ __launch_bounds__(SCB)
void scan2_kernel(int* __restrict__ bsum, int nb)
{
    __shared__ int s[SCB];
    const int v = (threadIdx.x < nb) ? bsum[threadIdx.x] : 0;
    s[threadIdx.x] = v;
    __syncthreads();
    #pragma unroll
    for (int off = 1; off < SCB; off <<= 1) {
        int t = (threadIdx.x >= off) ? s[threadIdx.x - off] : 0;
        __syncthreads();
        s[threadIdx.x] += t;
        __syncthreads();
    }
    if (threadIdx.x < nb) bsum[threadIdx.x] = s[threadIdx.x] - v;
}

__global__ __launch_bounds__(SCB)
void scan3_kernel(int* __restrict__ exc, const int* __restrict__ bsum, int n)
{
    const int i = blockIdx.x * SCB + (int)threadIdx.x;
    if (i < n) exc[i] += bsum[i >> 8];
}

__global__ __launch_bounds__(256)
void scatter_kernel(const int* __restrict__ idx_i, const int* __restrict__ idx_j,
                    int* __restrict__ cursor, int* __restrict__ perm,
                    int* __restrict__ si, int* __restrict__ sj, int E)
{
    const int e = blockIdx.x * 256 + threadIdx.x;
    if (e < E) {
        const int n = idx_i[e];
        const int p = atomicAdd(&cursor[n], 1);
        perm[p] = e;
        si[p] = n;
        sj[p] = idx_j[e];
    }
}

// ---------------------------------------------------------------------------
// barrier-free split-bf16 MFMA GEMM, A loaded DIRECTLY from global per lane.
//   rows r < nA: A0[r] (optionally u = a*s_prev*m_prev on the fly, read-only)
//   rows r >= nA: A1[r-nA]
//   out = (relu?)(A @ W) + bias (rows < bias_limit) -> out0 [, out1]
// 512 threads = 8 waves (2x4), 64x128 tile, C = Ahi*Whi + Ahi*Wlo + Alo*Whi.
// LDS = W hi/lo only (64.5 KB) -> 2 blocks/CU; no barriers in tile loop.
// ---------------------------------------------------------------------------
__global__ __launch_bounds__(512, 4)
void gemm_dir_kernel(const float* __restrict__ A0, const float* __restrict__ A1,
                     int nA, int nTotal,
                     const float* __restrict__ W, const float* __restrict__ bias,
                     int bias_limit, int do_relu, int update,
                     const float* __restrict__ s_prev, const int* __restrict__ m_prev,
                     float* __restrict__ out0, float* __restrict__ out1, int ntiles)
{
    // LDS: Whi 32K | Wlo 32K | bias 512   (Whi/Wlo overlaid by f32 W scratch in prologue)
    __shared__ __align__(16) unsigned char SM[66064];
    char*  const Whi = (char*)SM;
    char*  const Wlo = (char*)SM + 32768;
    float* const Wf  = (float*)SM;
    float* const bs  = (float*)(SM + 65536);

    const int t = (int)threadIdx.x;

    // prologue 1: coalesced W f32 -> LDS scratch
    {
        const float4* Wg = (const float4*)W;
        float4* Wd = (float4*)Wf;
        #pragma unroll
        for (int i = 0; i < 8; ++i) Wd[t + i * 512] = Wg[t + i * 512];
        if (t < DD) bs[t] = bias ? bias[t] : 0.f;
    }
    __syncthreads();
    // prologue 2: in-place transpose+split via registers
    {
        const int col = t & 127;
        const int kb  = (t >> 7) * 16;   // 0,16,32,48
        float v0[16], v1[16];
        #pragma unroll
        for (int j = 0; j < 16; ++j) {
            v0[j] = Wf[(size_t)(kb + j) * DD + col];
            v1[j] = Wf[(size_t)(kb + 64 + j) * DD + col];
        }
        __syncthreads();   // all reads done before in-place overwrite
        #pragma unroll
        for (int half = 0; half < 2; ++half) {
            const float* v = half ? v1 : v0;
            const int KB = kb + half * 64;
            #pragma unroll
            for (int c = 0; c < 2; ++c) {
                unsigned h8[8], l8[8];
                #pragma unroll
                for (int j = 0; j < 8; ++j) {
                    const float w0 = v[c * 8 + j];
                    const unsigned hb = bf16_rne(w0);
                    h8[j] = hb;
                    l8[j] = bf16_rne(w0 - __uint_as_float(hb << 16));
                }
                uint4 ph, pl;
                ph.x = h8[0] | (h8[1] << 16); ph.y = h8[2] | (h8[3] << 16);
                ph.z = h8[4] | (h8[5] << 16); ph.w = h8[6] | (h8[7] << 16);
                pl.x = l8[0] | (l8[1] << 16); pl.y = l8[2] | (l8[3] << 16);
                pl.z = l8[4] | (l8[5] << 16); pl.w = l8[6] | (l8[7] << 16);
                const int off = (col * 256 + (KB + c * 8) * 2) ^ ((col & 7) << 4);
                *(uint4*)(Whi + off) = ph;
                *(uint4*)(Wlo + off) = pl;
            }
        }
    }
    __syncthreads();

    const int w  = t >> 6;
    const int l  = t & 63;
    const int wm = w >> 2;     // 0..1 : 32-row block
    const int wn = w & 3;      // 0..3 : 32-col block
    const int g  = l >> 4;     // 0..3
    const int q  = l & 15;

    for (int tile = blockIdx.x; tile < ntiles; tile += gridDim.x) {
        const int r0 = tile * 64;
        f32x4 acc[2][2];
        const f32x4 zero = {0.f, 0.f, 0.f, 0.f};
        acc[0][0] = zero; acc[0][1] = zero; acc[1][0] = zero; acc[1][1] = zero;

        #pragma unroll
        for (int ks = 0; ks < 4; ++ks) {
            const int kf = ks * 32 + g * 8;
            bf16x8 ah[2], al[2];
            #pragma unroll
            for (int m = 0; m < 2; ++m) {
                const int rr = min(r0 + wm * 32 + m * 16 + q, nTotal - 1);
                float d[8];
                if (rr < nA) {
                    const float* pa = A0 + (size_t)rr * DD + kf;
                    const float4 a0 = *(const float4*)pa;
                    const float4 a1 = *(const float4*)(pa + 4);
                    if (update) {
                        const float* sp = s_prev + (size_t)rr * DD + kf;
                        const int*   mp = m_prev + (size_t)rr * DD + kf;
                        const float4 s0 = *(const float4*)sp;
                        const float4 s1 = *(const float4*)(sp + 4);
                        const int4   i0 = *(const int4*)mp;
                        const int4   i1 = *(const int4*)(mp + 4);
                        d[0] = a0.x * s0.x * __int_as_float(i0.x);
                        d[1] = a0.y * s0.y * __int_as_float(i0.y);
                        d[2] = a0.z * s0.z * __int_as_float(i0.z);
                        d[3] = a0.w * s0.w * __int_as_float(i0.w);
                        d[4] = a1.x * s1.x * __int_as_float(i1.x);
                        d[5] = a1.y * s1.y * __int_as_float(i1.y);
                        d[6] = a1.z * s1.z * __int_as_float(i1.z);
                        d[7] = a1.w * s1.w * __int_as_float(i1.w);
                    } else {
                        d[0] = a0.x; d[1] = a0.y; d[2] = a0.z; d[3] = a0.w;
                        d[4] = a1.x; d[5] = a1.y; d[6] = a1.z; d[7] = a1.w;
                    }
                } else {
                    const float* pa = A1 + (size_t)(rr - nA) * DD + kf;
                    const float4 a0 = *(const float4*)pa;
                    const float4 a1 = *(const float4*)(pa + 4);
                    d[0] = a0.x; d[1] = a0.y; d[2] = a0.z; d[3] = a0.w;
                    d[4] = a1.x; d[5] = a1.y; d[6] = a1.z; d[7] = a1.w;
                }
                unsigned h8[8], l8[8];
                #pragma unroll
                for (int j = 0; j < 8; ++j) {
                    const unsigned hb = bf16_rne(d[j]);
                    h8[j] = hb;
                    l8[j] = bf16_rne(d[j] - __uint_as_float(hb << 16));
                }
                uint4 ph, pl;
                ph.x = h8[0] | (h8[1] << 16); ph.y = h8[2] | (h8[3] << 16);
                ph.z = h8[4] | (h8[5] << 16); ph.w = h8[6] | (h8[7] << 16);
                pl.x = l8[0] | (l8[1] << 16); pl.y = l8[2] | (l8[3] << 16);
                pl.z = l8[4] | (l8[5] << 16); pl.w = l8[6] | (l8[7] << 16);
                ah[m] = *(bf16x8*)&ph;
                al[m] = *(bf16x8*)&pl;
            }
            bf16x8 bh[2], bl[2];
            #pragma unroll
            for (int n = 0; n < 2; ++n) {
                const int colv = wn * 32 + n * 16 + q;
                const int off = (colv * 256 + ks * 64 + g * 16) ^ ((colv & 7) << 4);
                bh[n] = *(const bf16x8*)(Whi + off);
                bl[n] = *(const bf16x8*)(Wlo + off);
            }
            #pragma unroll
            for (int m = 0; m < 2; ++m)
                #pragma unroll
                for (int n = 0; n < 2; ++n) {
                    acc[m][n] = __builtin_amdgcn_mfma_f32_16x16x32_bf16(ah[m], bh[n], acc[m][n], 0, 0, 0);
                    acc[m][n] = __builtin_amdgcn_mfma_f32_16x16x32_bf16(ah[m], bl[n], acc[m][n], 0, 0, 0);
                    acc[m][n] = __builtin_amdgcn_mfma_f32_16x16x32_bf16(al[m], bh[n], acc[m][n], 0, 0, 0);
                }
        }

        // epilogue
        #pragma unroll
        for (int n = 0; n < 2; ++n) {
            const int colv = wn * 32 + n * 16 + q;
            const float bv = bs[colv];
            #pragma unroll
            for (int m = 0; m < 2; ++m) {
                #pragma unroll
                for (int r = 0; r < 4; ++r) {
                    const int row = r0 + wm * 32 + m * 16 + g * 4 + r;
                    if (row < nTotal) {
                        float v = acc[m][n][r] + ((row < bias_limit) ? bv : 0.f);
                        if (do_relu) v = fmaxf(v, 0.f);
                        out0[(size_t)row * DD + colv] = v;
                        if (out1) out1[(size_t)row * DD + colv] = v;
                    }
                }
            }
        }
    }
}

// ---------------------------------------------------------------------------
// bond projection via packed-split MFMA + fused sorted aggregation:
//   hb = relu(edge_attr[perm] @ Wb + bb), K=16 padded to 32 by the split:
//   Apack=[ahi|alo]; MFMA1 with [whi|wlo] + MFMA2 with [wlo|whi] = exact split.
// 512 threads = 8 waves (2x4), 64 edges x 128 cols per tile.
// ---------------------------------------------------------------------------
__global__ __launch_bounds__(512, 4)
void bond_mfma_kernel(const float* __restrict__ edge_attr,
                      const float* __restrict__ Wb, const float* __restrict__ bb,
                      const int* __restrict__ si, const int* __restrict__ perm,
                      float* __restrict__ h_head0,
                      float* __restrict__ sum_agg, int* __restrict__ max_agg,
                      int E, int N, int ntiles)
{
    // LDS: Ap [64][80B]=5120 | B1 [128][80B]=10240 | B2 10240 | bias 512 | ii 256 | pm 256
    __shared__ __align__(16) unsigned char SM[26640];
    char*  const Ap  = (char*)SM;
    char*  const B1  = (char*)SM + 5120;
    char*  const B2  = (char*)SM + 15360;
    float* const bsh = (float*)(SM + 25600);
    int*   const ii_s = (int*)(SM + 26112);
    int*   const pm_s = (int*)(SM + 26368);

    const int t = (int)threadIdx.x;

    // stage W packs (once): thread handles (col, 4-k quad)
    {
        const int col = t & 127;
        const int kq  = t >> 7;   // 0..3
        unsigned hq[4], lq[4];
        #pragma unroll
        for (int j = 0; j < 4; ++j) {
            const float w0 = Wb[(size_t)(kq * 4 + j) * DD + col];
            const unsigned hb = bf16_rne(w0);
            hq[j] = hb;
            lq[j] = bf16_rne(w0 - __uint_as_float(hb << 16));
        }
        uint2 ph, pl;
        ph.x = hq[0] | (hq[1] << 16); ph.y = hq[2] | (hq[3] << 16);
        pl.x = lq[0] | (lq[1] << 16); pl.y = lq[2] | (lq[3] << 16);
        *(uint2*)(B1 + col * 80 + kq * 8)      = ph;   // k 0..15  = whi
        *(uint2*)(B1 + col * 80 + 32 + kq * 8) = pl;   // k 16..31 = wlo
        *(uint2*)(B2 + col * 80 + kq * 8)      = pl;   // k 0..15  = wlo
        *(uint2*)(B2 + col * 80 + 32 + kq * 8) = ph;   // k 16..31 = whi
        if (t < DD) bsh[t] = bb[t];
    }

    const int w  = t >> 6;
    const int l  = t & 63;
    const int wm = w >> 2;   // 0..1
    const int wn = w & 3;    // 0..3
    const int g  = l >> 4;
    const int q  = l & 15;

    const int per = (ntiles + (int)gridDim.x - 1) / (int)gridDim.x;
    const int t0 = blockIdx.x * per;
    const int t1 = min(t0 + per, ntiles);

    for (int tile = t0; tile < t1; ++tile) {
        const int e0 = tile * 64;
        __syncthreads();   // prev tile readers done; also fences W-pack on iter 0

        // stage indices + A tile (gather via perm, split, pack)
        if (t < 64) {
            const int p = min(e0 + t, E - 1);
            ii_s[t] = si[p];
            pm_s[t] = perm[p];
        }
        if (t < 256) {
            const int row  = t >> 2;
            const int c4   = t & 3;
            const int p    = min(e0 + row, E - 1);
            const int orig = perm[p];
            const float4 a = *(const float4*)(edge_attr + (size_t)orig * 16 + c4 * 4);
            unsigned h4[4], l4[4];
            h4[0] = bf16_rne(a.x); l4[0] = bf16_rne(a.x - __uint_as_float(h4[0] << 16));
            h4[1] = bf16_rne(a.y); l4[1] = bf16_rne(a.y - __uint_as_float(h4[1] << 16));
            h4[2] = bf16_rne(a.z); l4[2] = bf16_rne(a.z - __uint_as_float(h4[2] << 16));
            h4[3] = bf16_rne(a.w); l4[3] = bf16_rne(a.w - __uint_as_float(h4[3] << 16));
            uint2 ph, pl;
            ph.x = h4[0] | (h4[1] << 16); ph.y = h4[2] | (h4[3] << 16);
            pl.x = l4[0] | (l4[1] << 16); pl.y = l4[2] | (l4[3] << 16);
            *(uint2*)(Ap + row * 80 + c4 * 8)      = ph;   // ahi at k 0..15
            *(uint2*)(Ap + row * 80 + 32 + c4 * 8) = pl;   // alo at k 16..31
        }
        __syncthreads();

        // MFMA: K=32, 2 per (m,n)
        f32x4 acc[2][2];
        const f32x4 zero = {0.f, 0.f, 0.f, 0.f};
        acc[0][0] = zero; acc[0][1] = zero; acc[1][0] = zero; acc[1][1] = zero;
        bf16x8 av[2];
        #pragma unroll
        for (int m = 0; m < 2; ++m)
            av[m] = *(const bf16x8*)(Ap + (wm * 32 + m * 16 + q) * 80 + g * 16);
        #pragma unroll
        for (int n = 0; n < 2; ++n) {
            const int colv = wn * 32 + n * 16 + q;
            const bf16x8 b1 = *(const bf16x8*)(B1 + colv * 80 + g * 16);
            const bf16x8 b2 = *(const bf16x8*)(B2 + colv * 80 + g * 16);
            #pragma unroll
            for (int m = 0; m < 2; ++m) {
                acc[m][n] = __builtin_amdgcn_mfma_f32_16x16x32_bf16(av[m], b1, acc[m][n], 0, 0, 0);
                acc[m][n] = __builtin_amdgcn_mfma_f32_16x16x32_bf16(av[m], b2, acc[m][n], 0, 0, 0);
            }
        }

        // epilogue: relu(+bias), head store, run-length atomics
        #pragma unroll
        for (int n = 0; n < 2; ++n) {
            const int colv = wn * 32 + n * 16 + q;
            const float bcol = bsh[colv];
            #pragma unroll
            for (int m = 0; m < 2; ++m) {
                const int rr0 = wm * 32 + m * 16 + g * 4;
                int node = ii_s[rr0];
                float rs = 0.f, rm = 0.f;
                #pragma unroll
                for (int r = 0; r < 4; ++r) {
                    const int row = rr0 + r;
                    const int e = e0 + row;
                    float v = fmaxf(acc[m][n][r] + bcol, 0.f);
                    if (e < E) {
                        const int orig = pm_s[row];
                        if (orig < N) h_head0[(size_t)orig * DD + colv] = v;
                    } else {
                        v = 0.f;
                    }
                    const int nd2 = ii_s[row];
                    if (nd2 != node) {
                        atomicAdd(&sum_agg[(size_t)node * DD + colv], rs);
                        atomicMax(&max_agg[(size_t)node * DD + colv], __float_as_int(rm));
                        node = nd2; rs = v; rm = v;
                    } else {
                        rs += v; rm = fmaxf(rm, v);
                    }
                }
                atomicAdd(&sum_agg[(size_t)node * DD + colv], rs);
                atomicMax(&max_agg[(size_t)node * DD + colv], __float_as_int(rm));
            }
        }
    }
}

// ---------------------------------------------------------------------------
// edge pass: phase 0 = node writeback h*=s_prev*m_prev + zero prev aggs;
// phase 1 = v = relu(P[si]-Q[sj]), run-length sum/max atomics into CUR aggs.
// ---------------------------------------------------------------------------
__global__ __launch_bounds__(256)
void edge_pass_kernel(const float* __restrict__ PQ,
                      const int* __restrict__ si, const int* __restrict__ sj,
                      const int* __restrict__ perm,
                      float* __restrict__ head_next, int store_head,
                      float* __restrict__ sum_agg, int* __restrict__ max_agg,
                      float* __restrict__ h_atom,
                      float* __restrict__ s_prev, int* __restrict__ m_prev, int nd4,
                      int E, int N)
{
    const int t = (int)threadIdx.x;

    // phase 0: fused node update + zero of previous-layer aggs
    for (int i = blockIdx.x * 256 + t; i < nd4; i += gridDim.x * 256) {
        float4 h = ((const float4*)h_atom)[i];
        const float4 s = ((const float4*)s_prev)[i];
        const int4  mm = ((const int4*)m_prev)[i];
        h.x *= s.x * __int_as_float(mm.x);
        h.y *= s.y * __int_as_float(mm.y);
        h.z *= s.z * __int_as_float(mm.z);
        h.w *= s.w * __int_as_float(mm.w);
        ((float4*)h_atom)[i] = h;
        ((float4*)s_prev)[i] = make_float4(0.f, 0.f, 0.f, 0.f);
        ((int4*)m_prev)[i]   = make_int4(0, 0, 0, 0);
    }

    __shared__ int si_s[CE], sj_s[CE], pm_s[CE];
    const int p0b = blockIdx.x * CE;
    if (p0b >= E) return;
    {
        const int p = min(p0b + t, E - 1);
        si_s[t] = si[p];
        sj_s[t] = sj[p];
        pm_s[t] = perm[p];
    }
    __syncthreads();

    const int w    = t >> 6;
    const int lane = t & 63;
    const int c    = lane * 2;
    const int q0   = w * 64;
    const int pg0  = p0b + q0;
    if (pg0 >= E) return;

    const float* __restrict__ Qbase = PQ + (size_t)N * DD + c;

    float2 qa = *(const float2*)(Qbase + (size_t)sj_s[q0 + 0] * DD);
    float2 qb = *(const float2*)(Qbase + (size_t)sj_s[q0 + 1] * DD);
    float2 qc = *(const float2*)(Qbase + (size_t)sj_s[q0 + 2] * DD);
    float2 qd = *(const float2*)(Qbase + (size_t)sj_s[q0 + 3] * DD);

    int curNode = si_s[q0];
    float2 Pi = *(const float2*)(PQ + (size_t)curNode * DD + c);
    float2 rs = make_float2(0.f, 0.f), rm = make_float2(0.f, 0.f);

    #define EP_STEP(K, QREG)                                                     \
    {                                                                            \
        const int kk = (K);                                                      \
        const int i = si_s[q0 + kk];                                             \
        if (i != curNode) {                                                      \
            atomicAdd(&sum_agg[(size_t)curNode * DD + c],     rs.x);             \
            atomicAdd(&sum_agg[(size_t)curNode * DD + c + 1], rs.y);             \
            atomicMax(&max_agg[(size_t)curNode * DD + c],     __float_as_int(rm.x)); \
            atomicMax(&max_agg[(size_t)curNode * DD + c + 1], __float_as_int(rm.y)); \
            curNode = i;                                                         \
            Pi = *(const float2*)(PQ + (size_t)i * DD + c);                      \
            rs = make_float2(0.f, 0.f);                                          \
            rm = make_float2(0.f, 0.f);                                          \
        }                                                                        \
        float2 v;                                                                \
        v.x = fmaxf(Pi.x - QREG.x, 0.f);                                         \
        v.y = fmaxf(Pi.y - QREG.y, 0.f);                                         \
        if (pg0 + kk >= E) { v.x = 0.f; v.y = 0.f; }                             \
        rs.x += v.x; rs.y += v.y;                                                \
        rm.x = fmaxf(rm.x, v.x); rm.y = fmaxf(rm.y, v.y);                        \
        if (store_head && (pg0 + kk) < E) {                                      \
            const int orig = pm_s[q0 + kk];                                      \
            if (orig < N) *(float2*)(head_next + (size_t)orig * DD + c) = v;     \
        }                                                                        \
        if (kk + 4 < 64)                                                         \
            QREG = *(const float2*)(Qbase + (size_t)sj_s[q0 + kk + 4] * DD);     \
    }

    #pragma unroll
    for (int k = 0; k < 64; k += 4) {
        EP_STEP(k + 0, qa);
        EP_STEP(k + 1, qb);
        EP_STEP(k + 2, qc);
        EP_STEP(k + 3, qd);
    }
    #undef EP_STEP

    atomicAdd(&sum_agg[(size_t)curNode * DD + c],     rs.x);
    atomicAdd(&sum_agg[(size_t)curNode * DD + c + 1], rs.y);
    atomicMax(&max_agg[(size_t)curNode * DD + c],     __float_as_int(rm.x));
    atomicMax(&max_agg[(size_t)curNode * DD + c + 1], __float_as_int(rm.y));
}

// ---------------------------------------------------------------------------
// final: out = [ha, x_proj] @ W_lin + b_lin via split-bf16 MFMA, K=256,
// ha = h*(h*sum*max) computed on the fly per lane. 512 thr = 8 waves (4x2),
// 128 rows x 64 cols per block.
// ---------------------------------------------------------------------------
__global__ __launch_bounds__(512, 2)
void final_mfma_kernel(const float* __restrict__ h, const float* __restrict__ sum_agg,
                       const int* __restrict__ max_agg, const float* __restrict__ xp,
                       const float* __restrict__ Wl, const float* __restrict__ bl,
                       float* __restrict__ out, int N)
{
    // LDS: Whi 32K | Wlo 32K | bias 256  (overlaid f32 scratch during prologue)
    __shared__ __align__(16) unsigned char SM[65808];
    char*  const Whi = (char*)SM;
    char*  const Wlo = (char*)SM + 32768;
    float* const Wf  = (float*)SM;
    float* const bs  = (float*)(SM + 65536);

    const int t = (int)threadIdx.x;
    {
        const float4* Wg = (const float4*)Wl;
        float4* Wd = (float4*)Wf;
        #pragma unroll
        for (int i = 0; i < 8; ++i) Wd[t + i * 512] = Wg[t + i * 512];
        if (t < 64) bs[t] = bl[t];
    }
    __syncthreads();
    {
        const int col = t & 63;
        const int kb  = (t >> 6) * 32;   // 0..224
        float v[32];
        #pragma unroll
        for (int j = 0; j < 32; ++j) v[j] = Wf[(size_t)(kb + j) * 64 + col];
        __syncthreads();
        #pragma unroll
        for (int c = 0; c < 4; ++c) {
            unsigned h8[8], l8[8];
            #pragma unroll
            for (int j = 0; j < 8; ++j) {
                const float w0 = v[c * 8 + j];
                const unsigned hb = bf16_rne(w0);
                h8[j] = hb;
                l8[j] = bf16_rne(w0 - __uint_as_float(hb << 16));
            }
            uint4 ph, pl;
            ph.x = h8[0] | (h8[1] << 16); ph.y = h8[2] | (h8[3] << 16);
            ph.z = h8[4] | (h8[5] << 16); ph.w = h8[6] | (h8[7] << 16);
            pl.x = l8[0] | (l8[1] << 16); pl.y = l8[2] | (l8[3] << 16);
            pl.z = l8[4] | (l8[5] << 16); pl.w = l8[6] | (l8[7] << 16);
            const int off = (col * 512 + (kb + c * 8) * 2) ^ ((col & 7) << 4);
            *(uint4*)(Whi + off) = ph;
            *(uint4*)(Wlo + off) = pl;
        }
    }
    __syncthreads();

    const int w  = t >> 6;
    const int l  = t & 63;
    const int wm = w >> 1;    // 0..3 : 32-row block
    const int wn = w & 1;     // 0..1 : 32-col block
    const int g  = l >> 4;
    const int q  = l & 15;
    const int r0 = (int)blockIdx.x * 128;

    f32x4 acc[2][2];
    const f32x4 zero = {0.f, 0.f, 0.f, 0.f};
    acc[0][0] = zero; acc[0][1] = zero; acc[1][0] = zero; acc[1][1] = zero;

    #pragma unroll
    for (int ks = 0; ks < 8; ++ks) {
        const int kf = (ks & 3) * 32 + g * 8;
        bf16x8 ah[2], al[2];
        #pragma unroll
        for (int m = 0; m < 2; ++m) {
            const int rr = min(r0 + wm * 32 + m * 16 + q, N - 1);
            float d[8];
            if (ks < 4) {
                const float* ph = h       + (size_t)rr * DD + kf;
                const float* ps = sum_agg + (size_t)rr * DD + kf;
                const int*   pm = max_agg + (size_t)rr * DD + kf;
                const float4 a0 = *(const float4*)ph;
                const float4 a1 = *(const float4*)(ph + 4);
                const float4 s0 = *(const float4*)ps;
                const float4 s1 = *(const float4*)(ps + 4);
                const int4   i0 = *(const int4*)pm;
                const int4   i1 = *(const int4*)(pm + 4);
                d[0] = a0.x * a0.x * s0.x * __int_as_float(i0.x);
                d[1] = a0.y * a0.y * s0.y * __int_as_float(i0.y);
                d[2] = a0.z * a0.z * s0.z * __int_as_float(i0.z);
                d[3] = a0.w * a0.w * s0.w * __int_as_float(i0.w);
                d[4] = a1.x * a1.x * s1.x * __int_as_float(i1.x);
                d[5] = a1.y * a1.y * s1.y * __int_as_float(i1.y);
                d[6] = a1.z * a1.z * s1.z * __int_as_float(i1.z);
                d[7] = a1.w * a1.w * s1.w * __int_as_float(i1.w);
            } else {
                const float* pa = xp + (size_t)rr * DD + kf;
                const float4 a0 = *(const float4*)pa;
                const float4 a1 = *(const float4*)(pa + 4);
                d[0] = a0.x; d[1] = a0.y; d[2] = a0.z; d[3] = a0.w;
                d[4] = a1.x; d[5] = a1.y; d[6] = a1.z; d[7] = a1.w;
            }
            unsigned h8[8], l8[8];
            #pragma unroll
            for (int j = 0; j < 8; ++j) {
                const unsigned hb = bf16_rne(d[j]);
                h8[j] = hb;
                l8[j] = bf16_rne(d[j] - __uint_as_float(hb << 16));
            }
            uint4 ph2, pl2;
            ph2.x = h8[0] | (h8[1] << 16); ph2.y = h8[2] | (h8[3] << 16);
            ph2.z = h8[4] | (h8[5] << 16); ph2.w = h8[6] | (h8[7] << 16);
            pl2.x = l8[0] | (l8[1] << 16); pl2.y = l8[2] | (l8[3] << 16);
            pl2.z = l8[4] | (l8[5] << 16); pl2.w = l8[6] | (l8[7] << 16);
            ah[m] = *(bf16x8*)&ph2;
            al[m] = *(bf16x8*)&pl2;
        }
        bf16x8 bh[2], blo[2];
        #pragma unroll
        for (int n = 0; n < 2; ++n) {
            const int colv = wn * 32 + n * 16 + q;
            const int off = (colv * 512 + ks * 64 + g * 16) ^ ((colv & 7) << 4);
            bh[n]  = *(const bf16x8*)(Whi + off);
            blo[n] = *(const bf16x8*)(Wlo + off);
        }
        #pragma unroll
        for (int m = 0; m < 2; ++m)
            #pragma unroll
            for (int n = 0; n < 2; ++n) {
                acc[m][n] = __builtin_amdgcn_mfma_f32_16x16x32_bf16(ah[m], bh[n],  acc[m][n], 0, 0, 0);
                acc[m][n] = __builtin_amdgcn_mfma_f32_16x16x32_bf16(ah[m], blo[n], acc[m][n], 0, 0, 0);
                acc[m][n] = __builtin_amdgcn_mfma_f32_16x16x32_bf16(al[m], bh[n],  acc[m][n], 0, 0, 0);
            }
    }

    #pragma unroll
    for (int n = 0; n < 2; ++n) {
        const int colv = wn * 32 + n * 16 + q;
        const float bv = bs[colv];
        #pragma unroll
        for (int m = 0; m < 2; ++m) {
            #pragma unroll
            for (int r = 0; r < 4; ++r) {
                const int row = r0 + wm * 32 + m * 16 + g * 4 + r;
                if (row < N) out[(size_t)row * 64 + colv] = acc[m][n][r] + bv;
            }
        }
    }
}

// ---------------------------------------------------------------------------
extern "C" void kernel_launch(void* const* d_in, const int* in_sizes, int n_in,
                              void* d_out, int out_size, void* d_ws, size_t ws_size,
                              hipStream_t stream)
{
    const float* x         = (const float*)d_in[0];
    const int*   edge_idx  = (const int*)d_in[1];
    const float* edge_attr = (const float*)d_in[2];
    const float* W_atom    = (const float*)d_in[3];
    const float* b_atom    = (const float*)d_in[4];
    const float* W_bond    = (const float*)d_in[5];
    const float* b_bond    = (const float*)d_in[6];
    const float* W_seq     = (const float*)d_in[7];
    const float* b_seq     = (const float*)d_in[8];
    const float* W_lin     = (const float*)d_in[9];
    const float* b_lin     = (const float*)d_in[10];
    float* out = (float*)d_out;

    const int N = in_sizes[0] / DD;   // 30000
    const int E = in_sizes[1] / 2;    // 480000
    const int* idx_i = edge_idx;
    const int* idx_j = edge_idx + E;

    const size_t nd = (size_t)N * DD;
    float* ws      = (float*)d_ws;
    float* x_proj  = ws;
    float* h_atom  = x_proj + nd;
    float* head    = h_atom + nd;
    float* sum0    = head + nd;
    int*   max0    = (int*)(sum0 + nd);
    float* sum1    = (float*)(max0 + nd);
    int*   max1    = (int*)(sum1 + nd);
    float* PQ      = (float*)(max1 + nd);      // 2N x 128
    int*   cnt     = (int*)(PQ + 2 * nd);
    int*   cursor  = cnt + N;
    int*   bsum    = cursor + N;
    int*   perm    = bsum + 256;
    int*   si      = perm + E;
    int*   sj      = si + E;

    // ---- counting sort of edges by idx_i ----
    hipMemsetAsync(cnt, 0, (size_t)N * 4, stream);
    hist_kernel<<<(E + 255) / 256, 256, 0, stream>>>(idx_i, cnt, E);
    const int nb_scan = (N + SCB - 1) / SCB;
    scan1_kernel<<<nb_scan, SCB, 0, stream>>>(cnt, cursor, bsum, N);
    scan2_kernel<<<1, SCB, 0, stream>>>(bsum, nb_scan);
    scan3_kernel<<<nb_scan, SCB, 0, stream>>>(cursor, bsum, N);
    scatter_kernel<<<(E + 255) / 256, 256, 0, stream>>>(idx_i, idx_j, cursor, perm, si, sj, E);

    hipMemsetAsync(sum0, 0, nd * 4, stream);
    hipMemsetAsync(max0, 0, nd * 4, stream);
    hipMemsetAsync(sum1, 0, nd * 4, stream);
    hipMemsetAsync(max1, 0, nd * 4, stream);

    // node projection: x_proj = h_atom = relu(x @ W_atom + b_atom)
    const int ntiles_n = (N + 63) / 64;
    gemm_dir_kernel<<<ntiles_n, 512, 0, stream>>>(
        x, x, N, N, W_atom, b_atom, N, 1, 0, nullptr, nullptr,
        x_proj, h_atom, ntiles_n);

    // bond projection + layer-0 aggregation -> B0
    const int ntiles_b = (E + 63) / 64;
    bond_mfma_kernel<<<1024, 512, 0, stream>>>(edge_attr, W_bond, b_bond,
                                               si, perm, head, sum0, max0,
                                               E, N, ntiles_b);

    const int ntiles_pq = (2 * N + 63) / 64;
    const int ep_blocks = (E + CE - 1) / CE;
    const int nd4 = (int)(nd / 4);

    float* sA = sum0; int* mA = max0;   // prev aggs for layer l
    float* sB = sum1; int* mB = max1;   // cur aggs for layer l
    for (int ll = 0; ll < 3; ++ll) {
        // PQ = [u; head] @ W_seq[l], u = h*sA*mA on the fly; P rows get +b_seq
        gemm_dir_kernel<<<512, 512, 0, stream>>>(
            h_atom, head, N, 2 * N, W_seq + (size_t)ll * DD * DD,
            b_seq + (size_t)ll * DD, N, 0, 1, sA, mA,
            PQ, nullptr, ntiles_pq);
        // per-edge + fused node writeback (h*=sA*mA, zero sA/mA), atomics -> sB/mB
        edge_pass_kernel<<<ep_blocks, 256, 0, stream>>>(
            PQ, si, sj, perm, head, (ll < 2) ? 1 : 0, sB, mB,
            h_atom, sA, mA, nd4, E, N);
        float* tsp = sA; sA = sB; sB = tsp;
        int*   tmp = mA; mA = mB; mB = tmp;
    }

    // after loop: h_atom = u3, latest aggs in sA/mA
    final_mfma_kernel<<<(N + 127) / 128, 512, 0, stream>>>(
        h_atom, sA, (const int*)mA, x_proj, W_lin, b_lin, out, N);
}

// Round 7
// 452.421 us; speedup vs baseline: 1.7517x; 1.7517x over previous
//
#include <hip/hip_runtime.h>
#include <hip/hip_bf16.h>

#define DD 128   // hidden dim
#define SCB 256  // scan block size
#define CE  256  // edges per block in edge_pass

typedef __attribute__((ext_vector_type(8))) short bf16x8;
typedef __attribute__((ext_vector_type(4))) float f32x4;

__device__ __forceinline__ unsigned bf16_rne(float f) {
    unsigned u = __float_as_uint(f);
    return (u + 0x7fffu + ((u >> 16) & 1u)) >> 16;
}

// ---------------------------------------------------------------------------
// counting-sort preprocessing (sort edges by idx_i)
// ---------------------------------------------------------------------------
__global__ __launch_bounds__(256)
void hist_kernel(const int* __restrict__ idx_i, int* __restrict__ cnt, int E)
{
    const int e = blockIdx.x * 256 + threadIdx.x;
    if (e < E) atomicAdd(&cnt[idx_i[e]], 1);
}

__global__ __launch_bounds__(SCB)
void scan1_kernel(const int* __restrict__ cnt, int* __restrict__ exc,
                  int* __restrict__ bsum, int n)
{
    __shared__ int s[SCB];
    const int i = blockIdx.x * SCB + (int)threadIdx.x;
    const int v = (i < n) ? cnt[i] : 0;
    s[threadIdx.x] = v;
    __syncthreads();
    #pragma unroll
    for (int off = 1; off < SCB; off <<= 1) {
        int t = (threadIdx.x >= off) ? s[threadIdx.x - off] : 0;
        __syncthreads();
        s[threadIdx.x] += t;
        __syncthreads();
    }
    if (i < n) exc[i] = s[threadIdx.x] - v;
    if (threadIdx.x == SCB - 1) bsum[blockIdx.x] = s[threadIdx.x];
}

__global__ __launch_bounds__(SCB)
void scan2_kernel(int* __restrict__ bsum, int nb)
{
    __shared__ int s[SCB];
    const int v = (threadIdx.x < nb) ? bsum[threadIdx.x] : 0;
    s[threadIdx.x] = v;
    __syncthreads();
    #pragma unroll
    for (int off = 1; off < SCB; off <<= 1) {
        int t = (threadIdx.x >= off) ? s[threadIdx.x - off] : 0;
        __syncthreads();
        s[threadIdx.x] += t;
        __syncthreads();
    }
    if (threadIdx.x < nb) bsum[threadIdx.x] = s[threadIdx.x] - v;
}

__global__ __launch_bounds__(SCB)
void scan3_kernel(int* __restrict__ exc, const int* __restrict__ bsum, int n)
{
    const int i = blockIdx.x * SCB + (int)threadIdx.x;
    if (i < n) exc[i] += bsum[i >> 8];
}

__global__ __launch_bounds__(256)
void scatter_kernel(const int* __restrict__ idx_i, const int* __restrict__ idx_j,
                    int* __restrict__ cursor, int* __restrict__ perm,
                    int* __restrict__ si, int* __restrict__ sj, int E)
{
    const int e = blockIdx.x * 256 + threadIdx.x;
    if (e < E) {
        const int n = idx_i[e];
        const int p = atomicAdd(&cursor[n], 1);
        perm[p] = e;
        si[p] = n;
        sj[p] = idx_j[e];
    }
}

// ---------------------------------------------------------------------------
// generic 128-K split-bf16 MFMA GEMM with optional fused node-update:
//   rows r < nA read from A0 (optionally h = h*sum*max, written back, aggs
//   zeroed), else from A1 (row r-nA).
//   out = (relu?)(A @ W) + bias for rows < bias_limit  -> out0 [, out1]
// 1024 threads = 16 waves (4x4), 128x128 tile, C = Ahi*Whi + Ahi*Wlo + Alo*Whi
// ---------------------------------------------------------------------------
__global__ __launch_bounds__(1024)
void gemm128_mfma_kernel(float* __restrict__ A0, const float* __restrict__ A1,
                         int nA, int nTotal,
                         const float* __restrict__ W, const float* __restrict__ bias,
                         int bias_limit, int do_relu, int update,
                         float* __restrict__ sum_agg, int* __restrict__ max_agg,
                         float* __restrict__ out0, float* __restrict__ out1,
                         int ntiles)
{
    // LDS: Whi 32K | Wlo 32K | Ahi 32K | Alo 32K | bias 512
    __shared__ __align__(16) unsigned char SM[131584];
    char*  const Whi = (char*)SM;
    char*  const Wlo = (char*)SM + 32768;
    char*  const Ahi = (char*)SM + 65536;
    char*  const Alo = (char*)SM + 98304;
    float* const Wf  = (float*)(SM + 65536);
    float* const bs  = (float*)(SM + 131072);

    const int t = (int)threadIdx.x;

    // ---- prologue phase 1: coalesced W f32 -> LDS scratch ----
    {
        const float4* Wg = (const float4*)W;
        float4* Wd = (float4*)Wf;
        #pragma unroll
        for (int i = 0; i < 4; ++i) Wd[t + i * 1024] = Wg[t + i * 1024];
        if (t < DD) bs[t] = bias ? bias[t] : 0.f;
    }
    __syncthreads();
    // ---- prologue phase 2: split + transpose into Whi/Wlo ----
    {
        const int col = t >> 3;
        const int kb  = (t & 7) * 16;
        unsigned h16[16], l16[16];
        #pragma unroll
        for (int j = 0; j < 16; ++j) {
            const float w = Wf[(size_t)(kb + j) * DD + col];
            const unsigned hb = bf16_rne(w);
            const float hf = __uint_as_float(hb << 16);
            h16[j] = hb;
            l16[j] = bf16_rne(w - hf);
        }
        #pragma unroll
        for (int c = 0; c < 2; ++c) {
            uint4 ph, pl;
            ph.x = h16[c*8+0] | (h16[c*8+1] << 16);
            ph.y = h16[c*8+2] | (h16[c*8+3] << 16);
            ph.z = h16[c*8+4] | (h16[c*8+5] << 16);
            ph.w = h16[c*8+6] | (h16[c*8+7] << 16);
            pl.x = l16[c*8+0] | (l16[c*8+1] << 16);
            pl.y = l16[c*8+2] | (l16[c*8+3] << 16);
            pl.z = l16[c*8+4] | (l16[c*8+5] << 16);
            pl.w = l16[c*8+6] | (l16[c*8+7] << 16);
            const int off = ((col * 256 + (kb + c * 8) * 2)) ^ ((col & 7) << 4);
            *(uint4*)(Whi + off) = ph;
            *(uint4*)(Wlo + off) = pl;
        }
    }

    const int w  = t >> 6;
    const int l  = t & 63;
    const int wm = w >> 2;
    const int wn = w & 3;
    const int g  = l >> 4;
    const int q  = l & 15;

    for (int tile = blockIdx.x; tile < ntiles; tile += gridDim.x) {
        const int e0 = tile * 128;
        __syncthreads();

        // ---- stage A tile (+ optional fused node-update), swizzled write ----
        #pragma unroll
        for (int i = 0; i < 2; ++i) {
            const int task = t + i * 1024;
            const int row  = task >> 4;
            const int c    = task & 15;
            const int rr = min(e0 + row, nTotal - 1);
            float d[8];
            if (rr < nA) {
                float* ph0 = A0 + (size_t)rr * DD + c * 8;
                const float4 a0 = *(const float4*)ph0;
                const float4 a1 = *(const float4*)(ph0 + 4);
                if (update) {
                    float* sp = sum_agg + (size_t)rr * DD + c * 8;
                    int*   mp = max_agg + (size_t)rr * DD + c * 8;
                    const float4 s0 = *(const float4*)sp;
                    const float4 s1 = *(const float4*)(sp + 4);
                    const int4   m0 = *(const int4*)mp;
                    const int4   m1 = *(const int4*)(mp + 4);
                    d[0] = a0.x * s0.x * __int_as_float(m0.x);
                    d[1] = a0.y * s0.y * __int_as_float(m0.y);
                    d[2] = a0.z * s0.z * __int_as_float(m0.z);
                    d[3] = a0.w * s0.w * __int_as_float(m0.w);
                    d[4] = a1.x * s1.x * __int_as_float(m1.x);
                    d[5] = a1.y * s1.y * __int_as_float(m1.y);
                    d[6] = a1.z * s1.z * __int_as_float(m1.z);
                    d[7] = a1.w * s1.w * __int_as_float(m1.w);
                    // write back updated h_atom; zero aggs for next layer
                    *(float4*)ph0       = make_float4(d[0], d[1], d[2], d[3]);
                    *(float4*)(ph0 + 4) = make_float4(d[4], d[5], d[6], d[7]);
                    *(float4*)sp       = make_float4(0.f, 0.f, 0.f, 0.f);
                    *(float4*)(sp + 4) = make_float4(0.f, 0.f, 0.f, 0.f);
                    *(int4*)mp       = make_int4(0, 0, 0, 0);
                    *(int4*)(mp + 4) = make_int4(0, 0, 0, 0);
                } else {
                    d[0] = a0.x; d[1] = a0.y; d[2] = a0.z; d[3] = a0.w;
                    d[4] = a1.x; d[5] = a1.y; d[6] = a1.z; d[7] = a1.w;
                }
            } else {
                const float* pa = A1 + (size_t)(rr - nA) * DD + c * 8;
                const float4 a0 = *(const float4*)pa;
                const float4 a1 = *(const float4*)(pa + 4);
                d[0] = a0.x; d[1] = a0.y; d[2] = a0.z; d[3] = a0.w;
                d[4] = a1.x; d[5] = a1.y; d[6] = a1.z; d[7] = a1.w;
            }
            unsigned h8[8], l8[8];
            #pragma unroll
            for (int j = 0; j < 8; ++j) {
                const unsigned hb = bf16_rne(d[j]);
                const float hf = __uint_as_float(hb << 16);
                h8[j] = hb;
                l8[j] = bf16_rne(d[j] - hf);
            }
            uint4 ph, pl;
            ph.x = h8[0] | (h8[1] << 16);
            ph.y = h8[2] | (h8[3] << 16);
            ph.z = h8[4] | (h8[5] << 16);
            ph.w = h8[6] | (h8[7] << 16);
            pl.x = l8[0] | (l8[1] << 16);
            pl.y = l8[2] | (l8[3] << 16);
            pl.z = l8[4] | (l8[5] << 16);
            pl.w = l8[6] | (l8[7] << 16);
            const int off = ((row * 256 + c * 16)) ^ ((row & 7) << 4);
            *(uint4*)(Ahi + off) = ph;
            *(uint4*)(Alo + off) = pl;
        }
        __syncthreads();

        // ---- MFMA ----
        f32x4 acc[2][2];
        const f32x4 zero = {0.f, 0.f, 0.f, 0.f};
        acc[0][0] = zero; acc[0][1] = zero; acc[1][0] = zero; acc[1][1] = zero;

        #pragma unroll
        for (int ks = 0; ks < 4; ++ks) {
            const int kbyte = ks * 64 + g * 16;
            bf16x8 ah[2], al[2], bh[2], bl[2];
            #pragma unroll
            for (int m = 0; m < 2; ++m) {
                const int row = wm * 32 + m * 16 + q;
                const int off = (row * 256 + kbyte) ^ ((row & 7) << 4);
                ah[m] = *(const bf16x8*)(Ahi + off);
                al[m] = *(const bf16x8*)(Alo + off);
            }
            #pragma unroll
            for (int n = 0; n < 2; ++n) {
                const int colv = wn * 32 + n * 16 + q;
                const int off = (colv * 256 + kbyte) ^ ((colv & 7) << 4);
                bh[n] = *(const bf16x8*)(Whi + off);
                bl[n] = *(const bf16x8*)(Wlo + off);
            }
            #pragma unroll
            for (int m = 0; m < 2; ++m)
                #pragma unroll
                for (int n = 0; n < 2; ++n)
                    acc[m][n] = __builtin_amdgcn_mfma_f32_16x16x32_bf16(ah[m], bh[n], acc[m][n], 0, 0, 0);
            #pragma unroll
            for (int m = 0; m < 2; ++m)
                #pragma unroll
                for (int n = 0; n < 2; ++n)
                    acc[m][n] = __builtin_amdgcn_mfma_f32_16x16x32_bf16(ah[m], bl[n], acc[m][n], 0, 0, 0);
            #pragma unroll
            for (int m = 0; m < 2; ++m)
                #pragma unroll
                for (int n = 0; n < 2; ++n)
                    acc[m][n] = __builtin_amdgcn_mfma_f32_16x16x32_bf16(al[m], bh[n], acc[m][n], 0, 0, 0);
        }

        // ---- epilogue: bias (rows < bias_limit) / relu + store ----
        #pragma unroll
        for (int n = 0; n < 2; ++n) {
            const int colv = wn * 32 + n * 16 + q;
            const float bv = bs[colv];
            #pragma unroll
            for (int m = 0; m < 2; ++m) {
                #pragma unroll
                for (int r = 0; r < 4; ++r) {
                    const int row = e0 + wm * 32 + m * 16 + g * 4 + r;
                    if (row < nTotal) {
                        float v = acc[m][n][r] + ((row < bias_limit) ? bv : 0.f);
                        if (do_relu) v = fmaxf(v, 0.f);
                        out0[(size_t)row * DD + colv] = v;
                        if (out1) out1[(size_t)row * DD + colv] = v;
                    }
                }
            }
        }
    }
}

// ---------------------------------------------------------------------------
// bond projection + layer-0 aggregation over SORTED edges (R5-proven VALU path)
// ---------------------------------------------------------------------------
__global__ __launch_bounds__(256)
void bond_proj_agg_kernel(const float* __restrict__ edge_attr,
                          const float* __restrict__ Wb, const float* __restrict__ bb,
                          const int* __restrict__ si, const int* __restrict__ perm,
                          float* __restrict__ h_head0,
                          float* __restrict__ sum_agg, int* __restrict__ max_agg,
                          int E, int N)
{
    __shared__ float Ws[16 * DD];
    __shared__ float bs2[DD];
    __shared__ __align__(16) float ea_s[32][16];
    __shared__ int ii2[32], pm2[32];

    for (int idx = (int)threadIdx.x; idx < 16 * DD; idx += 256) Ws[idx] = Wb[idx];
    if (threadIdx.x < DD) bs2[threadIdx.x] = bb[threadIdx.x];

    const int p0 = blockIdx.x * 32;
    {
        const int t = (int)threadIdx.x;
        const int row = t >> 3;
        const int k2 = (t & 7) * 2;
        const int ppc = min(p0 + row, E - 1);
        const int orig = perm[ppc];
        const float2 v2 = *(const float2*)(edge_attr + (size_t)orig * 16 + k2);
        ea_s[row][k2] = v2.x;
        ea_s[row][k2 + 1] = v2.y;
        if (t < 32) {
            const int q = min(p0 + t, E - 1);
            ii2[t] = si[q];
            pm2[t] = perm[q];
        }
    }
    __syncthreads();

    const int o    = threadIdx.x & 127;
    const int half = threadIdx.x >> 7;

    float wcol[16];
    #pragma unroll
    for (int k = 0; k < 16; ++k) wcol[k] = Ws[k * DD + o];
    const float bo = bs2[o];

    int curNode = ii2[half * 16];
    float rs = 0.f, rm = 0.f;
    #pragma unroll 4
    for (int j = 0; j < 16; ++j) {
        const int row = half * 16 + j;
        const float4* ear = (const float4*)(&ea_s[row][0]);
        const float4 q0 = ear[0], q1 = ear[1], q2 = ear[2], q3 = ear[3];
        float acc = bo;
        acc = fmaf(q0.x, wcol[ 0], acc);
        acc = fmaf(q0.y, wcol[ 1], acc);
        acc = fmaf(q0.z, wcol[ 2], acc);
        acc = fmaf(q0.w, wcol[ 3], acc);
        acc = fmaf(q1.x, wcol[ 4], acc);
        acc = fmaf(q1.y, wcol[ 5], acc);
        acc = fmaf(q1.z, wcol[ 6], acc);
        acc = fmaf(q1.w, wcol[ 7], acc);
        acc = fmaf(q2.x, wcol[ 8], acc);
        acc = fmaf(q2.y, wcol[ 9], acc);
        acc = fmaf(q2.z, wcol[10], acc);
        acc = fmaf(q2.w, wcol[11], acc);
        acc = fmaf(q3.x, wcol[12], acc);
        acc = fmaf(q3.y, wcol[13], acc);
        acc = fmaf(q3.z, wcol[14], acc);
        acc = fmaf(q3.w, wcol[15], acc);
        float v = fmaxf(acc, 0.f);
        const int pe = p0 + row;
        if (pe < E) {
            const int orig = pm2[row];
            if (orig < N) h_head0[(size_t)orig * DD + o] = v;
        } else {
            v = 0.f;
        }
        const int gi = ii2[row];
        if (gi != curNode) {
            atomicAdd(&sum_agg[(size_t)curNode * DD + o], rs);
            atomicMax(&max_agg[(size_t)curNode * DD + o], __float_as_int(rm));
            curNode = gi; rs = v; rm = v;
        } else {
            rs += v; rm = fmaxf(rm, v);
        }
    }
    atomicAdd(&sum_agg[(size_t)curNode * DD + o], rs);
    atomicMax(&max_agg[(size_t)curNode * DD + o], __float_as_int(rm));
}

// ---------------------------------------------------------------------------
// edge pass (linearized): v = relu(P[si[p]] - Q[sj[p]])   (bias folded into P)
//   P = PQ rows [0,N), Q = PQ rows [N,2N)
//   block stages si/sj/perm for CE edges into LDS; 4 waves x 64 edges each,
//   4-deep statically-indexed Q-row prefetch; run-length sum/max atomics.
// ---------------------------------------------------------------------------
__global__ __launch_bounds__(256)
void edge_pass_kernel(const float* __restrict__ PQ,
                      const int* __restrict__ si, const int* __restrict__ sj,
                      const int* __restrict__ perm,
                      float* __restrict__ head_next, int store_head,
                      float* __restrict__ sum_agg, int* __restrict__ max_agg,
                      int E, int N)
{
    __shared__ int si_s[CE], sj_s[CE], pm_s[CE];
    const int p0b = blockIdx.x * CE;
    if (p0b >= E) return;
    const int t = (int)threadIdx.x;
    {
        const int p = min(p0b + t, E - 1);
        si_s[t] = si[p];
        sj_s[t] = sj[p];
        pm_s[t] = perm[p];
    }
    __syncthreads();

    const int w    = t >> 6;
    const int lane = t & 63;
    const int c    = lane * 2;
    const int q0   = w * 64;
    const int pg0  = p0b + q0;
    if (pg0 >= E) return;

    const float* __restrict__ Qbase = PQ + (size_t)N * DD + c;

    float2 qa = *(const float2*)(Qbase + (size_t)sj_s[q0 + 0] * DD);
    float2 qb = *(const float2*)(Qbase + (size_t)sj_s[q0 + 1] * DD);
    float2 qc = *(const float2*)(Qbase + (size_t)sj_s[q0 + 2] * DD);
    float2 qd = *(const float2*)(Qbase + (size_t)sj_s[q0 + 3] * DD);

    int curNode = si_s[q0];
    float2 Pi = *(const float2*)(PQ + (size_t)curNode * DD + c);
    float2 rs = make_float2(0.f, 0.f), rm = make_float2(0.f, 0.f);

    #define EP_STEP(K, QREG)                                                     \
    {                                                                            \
        const int kk = (K);                                                      \
        const int i = si_s[q0 + kk];                                             \
        if (i != curNode) {                                                      \
            atomicAdd(&sum_agg[(size_t)curNode * DD + c],     rs.x);             \
            atomicAdd(&sum_agg[(size_t)curNode * DD + c + 1], rs.y);             \
            atomicMax(&max_agg[(size_t)curNode * DD + c],     __float_as_int(rm.x)); \
            atomicMax(&max_agg[(size_t)curNode * DD + c + 1], __float_as_int(rm.y)); \
            curNode = i;                                                         \
            Pi = *(const float2*)(PQ + (size_t)i * DD + c);                      \
            rs = make_float2(0.f, 0.f);                                          \
            rm = make_float2(0.f, 0.f);                                          \
        }                                                                        \
        float2 v;                                                                \
        v.x = fmaxf(Pi.x - QREG.x, 0.f);                                         \
        v.y = fmaxf(Pi.y - QREG.y, 0.f);                                         \
        if (pg0 + kk >= E) { v.x = 0.f; v.y = 0.f; }                             \
        rs.x += v.x; rs.y += v.y;                                                \
        rm.x = fmaxf(rm.x, v.x); rm.y = fmaxf(rm.y, v.y);                        \
        if (store_head && (pg0 + kk) < E) {                                      \
            const int orig = pm_s[q0 + kk];                                      \
            if (orig < N) *(float2*)(head_next + (size_t)orig * DD + c) = v;     \
        }                                                                        \
        if (kk + 4 < 64)                                                         \
            QREG = *(const float2*)(Qbase + (size_t)sj_s[q0 + kk + 4] * DD);     \
    }

    #pragma unroll
    for (int k = 0; k < 64; k += 4) {
        EP_STEP(k + 0, qa);
        EP_STEP(k + 1, qb);
        EP_STEP(k + 2, qc);
        EP_STEP(k + 3, qd);
    }
    #undef EP_STEP

    atomicAdd(&sum_agg[(size_t)curNode * DD + c],     rs.x);
    atomicAdd(&sum_agg[(size_t)curNode * DD + c + 1], rs.y);
    atomicMax(&max_agg[(size_t)curNode * DD + c],     __float_as_int(rm.x));
    atomicMax(&max_agg[(size_t)curNode * DD + c + 1], __float_as_int(rm.y));
}

// ---------------------------------------------------------------------------
// final: out = [ha, x_proj] @ W_lin + b_lin via split-bf16 MFMA, K=256,
// ha = h*(h*sum*max) computed on the fly per lane. 512 thr = 8 waves (4x2),
// 128 rows x 64 cols per block.
// ---------------------------------------------------------------------------
__global__ __launch_bounds__(512, 2)
void final_mfma_kernel(const float* __restrict__ h, const float* __restrict__ sum_agg,
                       const int* __restrict__ max_agg, const float* __restrict__ xp,
                       const float* __restrict__ Wl, const float* __restrict__ bl,
                       float* __restrict__ out, int N)
{
    // LDS: Whi 32K | Wlo 32K | bias 256  (overlaid f32 scratch during prologue)
    __shared__ __align__(16) unsigned char SM[65808];
    char*  const Whi = (char*)SM;
    char*  const Wlo = (char*)SM + 32768;
    float* const Wf  = (float*)SM;
    float* const bs  = (float*)(SM + 65536);

    const int t = (int)threadIdx.x;
    {
        const float4* Wg = (const float4*)Wl;
        float4* Wd = (float4*)Wf;
        #pragma unroll
        for (int i = 0; i < 8; ++i) Wd[t + i * 512] = Wg[t + i * 512];
        if (t < 64) bs[t] = bl[t];
    }
    __syncthreads();
    {
        const int col = t & 63;
        const int kb  = (t >> 6) * 32;   // 0..224
        float v[32];
        #pragma unroll
        for (int j = 0; j < 32; ++j) v[j] = Wf[(size_t)(kb + j) * 64 + col];
        __syncthreads();
        #pragma unroll
        for (int c = 0; c < 4; ++c) {
            unsigned h8[8], l8[8];
            #pragma unroll
            for (int j = 0; j < 8; ++j) {
                const float w0 = v[c * 8 + j];
                const unsigned hb = bf16_rne(w0);
                h8[j] = hb;
                l8[j] = bf16_rne(w0 - __uint_as_float(hb << 16));
            }
            uint4 ph, pl;
            ph.x = h8[0] | (h8[1] << 16); ph.y = h8[2] | (h8[3] << 16);
            ph.z = h8[4] | (h8[5] << 16); ph.w = h8[6] | (h8[7] << 16);
            pl.x = l8[0] | (l8[1] << 16); pl.y = l8[2] | (l8[3] << 16);
            pl.z = l8[4] | (l8[5] << 16); pl.w = l8[6] | (l8[7] << 16);
            const int off = (col * 512 + (kb + c * 8) * 2) ^ ((col & 7) << 4);
            *(uint4*)(Whi + off) = ph;
            *(uint4*)(Wlo + off) = pl;
        }
    }
    __syncthreads();

    const int w  = t >> 6;
    const int l  = t & 63;
    const int wm = w >> 1;    // 0..3 : 32-row block
    const int wn = w & 1;     // 0..1 : 32-col block
    const int g  = l >> 4;
    const int q  = l & 15;
    const int r0 = (int)blockIdx.x * 128;

    f32x4 acc[2][2];
    const f32x4 zero = {0.f, 0.f, 0.f, 0.f};
    acc[0][0] = zero; acc[0][1] = zero; acc[1][0] = zero; acc[1][1] = zero;

    #pragma unroll
    for (int ks = 0; ks < 8; ++ks) {
        const int kf = (ks & 3) * 32 + g * 8;
        bf16x8 ah[2], al[2];
        #pragma unroll
        for (int m = 0; m < 2; ++m) {
            const int rr = min(r0 + wm * 32 + m * 16 + q, N - 1);
            float d[8];
            if (ks < 4) {
                const float* ph = h       + (size_t)rr * DD + kf;
                const float* ps = sum_agg + (size_t)rr * DD + kf;
                const int*   pm = max_agg + (size_t)rr * DD + kf;
                const float4 a0 = *(const float4*)ph;
                const float4 a1 = *(const float4*)(ph + 4);
                const float4 s0 = *(const float4*)ps;
                const float4 s1 = *(const float4*)(ps + 4);
                const int4   i0 = *(const int4*)pm;
                const int4   i1 = *(const int4*)(pm + 4);
                d[0] = a0.x * a0.x * s0.x * __int_as_float(i0.x);
                d[1] = a0.y * a0.y * s0.y * __int_as_float(i0.y);
                d[2] = a0.z * a0.z * s0.z * __int_as_float(i0.z);
                d[3] = a0.w * a0.w * s0.w * __int_as_float(i0.w);
                d[4] = a1.x * a1.x * s1.x * __int_as_float(i1.x);
                d[5] = a1.y * a1.y * s1.y * __int_as_float(i1.y);
                d[6] = a1.z * a1.z * s1.z * __int_as_float(i1.z);
                d[7] = a1.w * a1.w * s1.w * __int_as_float(i1.w);
            } else {
                const float* pa = xp + (size_t)rr * DD + kf;
                const float4 a0 = *(const float4*)pa;
                const float4 a1 = *(const float4*)(pa + 4);
                d[0] = a0.x; d[1] = a0.y; d[2] = a0.z; d[3] = a0.w;
                d[4] = a1.x; d[5] = a1.y; d[6] = a1.z; d[7] = a1.w;
            }
            unsigned h8[8], l8[8];
            #pragma unroll
            for (int j = 0; j < 8; ++j) {
                const unsigned hb = bf16_rne(d[j]);
                h8[j] = hb;
                l8[j] = bf16_rne(d[j] - __uint_as_float(hb << 16));
            }
            uint4 ph2, pl2;
            ph2.x = h8[0] | (h8[1] << 16); ph2.y = h8[2] | (h8[3] << 16);
            ph2.z = h8[4] | (h8[5] << 16); ph2.w = h8[6] | (h8[7] << 16);
            pl2.x = l8[0] | (l8[1] << 16); pl2.y = l8[2] | (l8[3] << 16);
            pl2.z = l8[4] | (l8[5] << 16); pl2.w = l8[6] | (l8[7] << 16);
            ah[m] = *(bf16x8*)&ph2;
            al[m] = *(bf16x8*)&pl2;
        }
        bf16x8 bh[2], blo[2];
        #pragma unroll
        for (int n = 0; n < 2; ++n) {
            const int colv = wn * 32 + n * 16 + q;
            const int off = (colv * 512 + ks * 64 + g * 16) ^ ((colv & 7) << 4);
            bh[n]  = *(const bf16x8*)(Whi + off);
            blo[n] = *(const bf16x8*)(Wlo + off);
        }
        #pragma unroll
        for (int m = 0; m < 2; ++m)
            #pragma unroll
            for (int n = 0; n < 2; ++n) {
                acc[m][n] = __builtin_amdgcn_mfma_f32_16x16x32_bf16(ah[m], bh[n],  acc[m][n], 0, 0, 0);
                acc[m][n] = __builtin_amdgcn_mfma_f32_16x16x32_bf16(ah[m], blo[n], acc[m][n], 0, 0, 0);
                acc[m][n] = __builtin_amdgcn_mfma_f32_16x16x32_bf16(al[m], bh[n],  acc[m][n], 0, 0, 0);
            }
    }

    #pragma unroll
    for (int n = 0; n < 2; ++n) {
        const int colv = wn * 32 + n * 16 + q;
        const float bv = bs[colv];
        #pragma unroll
        for (int m = 0; m < 2; ++m) {
            #pragma unroll
            for (int r = 0; r < 4; ++r) {
                const int row = r0 + wm * 32 + m * 16 + g * 4 + r;
                if (row < N) out[(size_t)row * 64 + colv] = acc[m][n][r] + bv;
            }
        }
    }
}

// ---------------------------------------------------------------------------
extern "C" void kernel_launch(void* const* d_in, const int* in_sizes, int n_in,
                              void* d_out, int out_size, void* d_ws, size_t ws_size,
                              hipStream_t stream)
{
    const float* x         = (const float*)d_in[0];
    const int*   edge_idx  = (const int*)d_in[1];
    const float* edge_attr = (const float*)d_in[2];
    const float* W_atom    = (const float*)d_in[3];
    const float* b_atom    = (const float*)d_in[4];
    const float* W_bond    = (const float*)d_in[5];
    const float* b_bond    = (const float*)d_in[6];
    const float* W_seq     = (const float*)d_in[7];
    const float* b_seq     = (const float*)d_in[8];
    const float* W_lin     = (const float*)d_in[9];
    const float* b_lin     = (const float*)d_in[10];
    float* out = (float*)d_out;

    const int N = in_sizes[0] / DD;   // 30000
    const int E = in_sizes[1] / 2;    // 480000
    const int* idx_i = edge_idx;
    const int* idx_j = edge_idx + E;

    const size_t nd = (size_t)N * DD;
    float* ws      = (float*)d_ws;
    float* x_proj  = ws;
    float* h_atom  = x_proj + nd;
    float* head    = h_atom + nd;       // single head buffer (edge pass reads only PQ)
    float* sum_agg = head + nd;
    int*   max_agg = (int*)(sum_agg + nd);
    float* PQ      = (float*)(max_agg + nd);   // 2N x 128
    int*   cnt     = (int*)(PQ + 2 * nd);
    int*   cursor  = cnt + N;
    int*   bsum    = cursor + N;
    int*   perm    = bsum + 256;
    int*   si      = perm + E;
    int*   sj      = si + E;

    // ---- counting sort of edges by idx_i ----
    hipMemsetAsync(cnt, 0, (size_t)N * 4, stream);
    hist_kernel<<<(E + 255) / 256, 256, 0, stream>>>(idx_i, cnt, E);
    const int nb_scan = (N + SCB - 1) / SCB;
    scan1_kernel<<<nb_scan, SCB, 0, stream>>>(cnt, cursor, bsum, N);
    scan2_kernel<<<1, SCB, 0, stream>>>(bsum, nb_scan);
    scan3_kernel<<<nb_scan, SCB, 0, stream>>>(cursor, bsum, N);
    scatter_kernel<<<(E + 255) / 256, 256, 0, stream>>>(idx_i, idx_j, cursor, perm, si, sj, E);

    hipMemsetAsync(sum_agg, 0, nd * 4, stream);
    hipMemsetAsync(max_agg, 0, nd * 4, stream);

    // node projection via MFMA: x_proj = h_atom = relu(x @ W_atom + b_atom)
    const int ntiles_n = (N + 127) / 128;
    gemm128_mfma_kernel<<<min(ntiles_n, 256), 1024, 0, stream>>>(
        (float*)x, x, N, N, W_atom, b_atom, N, 1, 0, nullptr, nullptr,
        x_proj, h_atom, ntiles_n);

    bond_proj_agg_kernel<<<(E + 31) / 32, 256, 0, stream>>>(edge_attr, W_bond, b_bond,
                                                            si, perm, head,
                                                            sum_agg, max_agg, E, N);

    const int ntiles_pq = (2 * N + 127) / 128;
    const int ep_blocks = (E + CE - 1) / CE;
    for (int l = 0; l < 3; ++l) {
        // PQ = [(h_atom*=sum*max); head] @ W_seq[l]; P rows get +b_seq[l];
        // h_atom written back, aggs zeroed (fused node-update)
        gemm128_mfma_kernel<<<256, 1024, 0, stream>>>(
            h_atom, head, N, 2 * N, W_seq + (size_t)l * DD * DD,
            b_seq + (size_t)l * DD, N, 0, 1, sum_agg, max_agg,
            PQ, nullptr, ntiles_pq);
        // per-edge: v = relu(P[i] - Q[j]); aggregate; store head in place
        edge_pass_kernel<<<ep_blocks, 256, 0, stream>>>(
            PQ, si, sj, perm, head, (l < 2) ? 1 : 0, sum_agg, max_agg, E, N);
    }

    final_mfma_kernel<<<(N + 127) / 128, 512, 0, stream>>>(
        h_atom, sum_agg, (const int*)max_agg, x_proj, W_lin, b_lin, out, N);
}